// Round 8
// baseline (55.018 us; speedup 1.0000x reference)
//
#include <hip/hip_runtime.h>
#include <hip/hip_bf16.h>

// Problem dims (fixed): B=8, Q=256, K=256, D=256, H=256, DV=512
#define B_  8
#define Q_  256
#define K_  256
#define D_  256
#define H_  256
#define DV_ 512
#define QB  4            // q-rows per attn block

#define SCALE_2LOG2E 2.8853900817779268f   // 2*log2(e): exp(2x) = 2^(x*this)
#define LOG2E_F      1.4426950408889634f

// ---------------------------------------------------------------------------
// Kernel 1: projections + exponentiation (exp factorization):
//   Eq [B][Q][H]  = 2^((queries @ W_q) * 2log2e)
//   EkT[B][H][K]  = 2^((keys    @ W_k)^T * 2log2e)   (transposed)
// Flat 1D grid, b = id&7: batch-b blocks land on XCD b (dispatch round-robin),
// matching attn's decode -> producer/consumer L2 locality.
// ---------------------------------------------------------------------------
__global__ __launch_bounds__(256) void proj_kernel(
    const float* __restrict__ queries, const float* __restrict__ keys,
    const float* __restrict__ Wq, const float* __restrict__ Wk,
    float* __restrict__ Eq, float* __restrict__ EkT) {
  const int id = blockIdx.x;
  const int b  = id & 7;
  const bool kpath = (id >> 3) & 1;
  const int m0 = ((id >> 4) & 3) * 64;     // q-rows (qpath) or k-cols (kpath)
  const int h0 = ((id >> 6) & 3) * 64;
  const int tid = threadIdx.x;

  __shared__ float As[64][68];             // [d][row]: qpath row=q, kpath row=h
  __shared__ float Bs[64][68];             // [d][col]: qpath col=h, kpath col=k

  const int lr = tid >> 4;                 // 0..15 (load row)
  const int lc = (tid & 15) << 2;          // 0,4,...,60 (load col, float4)
  const int r0 = (tid & 15) << 2;          // micro-tile rows
  const int c0 = (tid >> 4) << 2;          // micro-tile cols

  float acc[4][4] = {};

  for (int kk = 0; kk < D_; kk += 64) {
    if (!kpath) {
      #pragma unroll
      for (int i = 0; i < 4; i++) {
        const int row = lr + i * 16;
        float4 va = *(const float4*)&queries[((size_t)(b * Q_ + m0 + row)) * D_ + kk + lc];
        As[lc + 0][row] = va.x; As[lc + 1][row] = va.y;
        As[lc + 2][row] = va.z; As[lc + 3][row] = va.w;
        float4 vb = *(const float4*)&Wq[((size_t)(kk + row)) * H_ + h0 + lc];
        *(float4*)&Bs[row][lc] = vb;
      }
    } else {
      #pragma unroll
      for (int i = 0; i < 4; i++) {
        const int row = lr + i * 16;
        float4 va = *(const float4*)&Wk[((size_t)(kk + row)) * H_ + h0 + lc];
        *(float4*)&As[row][lc] = va;
        float4 vb = *(const float4*)&keys[((size_t)(b * K_ + m0 + row)) * D_ + kk + lc];
        Bs[lc + 0][row] = vb.x; Bs[lc + 1][row] = vb.y;
        Bs[lc + 2][row] = vb.z; Bs[lc + 3][row] = vb.w;
      }
    }
    __syncthreads();

    #pragma unroll 8
    for (int d = 0; d < 64; d++) {
      float4 av = *(const float4*)&As[d][r0];
      float4 bv = *(const float4*)&Bs[d][c0];
      acc[0][0] = fmaf(av.x, bv.x, acc[0][0]); acc[0][1] = fmaf(av.x, bv.y, acc[0][1]);
      acc[0][2] = fmaf(av.x, bv.z, acc[0][2]); acc[0][3] = fmaf(av.x, bv.w, acc[0][3]);
      acc[1][0] = fmaf(av.y, bv.x, acc[1][0]); acc[1][1] = fmaf(av.y, bv.y, acc[1][1]);
      acc[1][2] = fmaf(av.y, bv.z, acc[1][2]); acc[1][3] = fmaf(av.y, bv.w, acc[1][3]);
      acc[2][0] = fmaf(av.z, bv.x, acc[2][0]); acc[2][1] = fmaf(av.z, bv.y, acc[2][1]);
      acc[2][2] = fmaf(av.z, bv.z, acc[2][2]); acc[2][3] = fmaf(av.z, bv.w, acc[2][3]);
      acc[3][0] = fmaf(av.w, bv.x, acc[3][0]); acc[3][1] = fmaf(av.w, bv.y, acc[3][1]);
      acc[3][2] = fmaf(av.w, bv.z, acc[3][2]); acc[3][3] = fmaf(av.w, bv.w, acc[3][3]);
    }
    __syncthreads();
  }

  float* dst = kpath ? EkT : Eq;
  const int ro = kpath ? h0 : m0, co = kpath ? m0 : h0;
  #pragma unroll
  for (int i = 0; i < 4; i++) {
    float4 v;
    v.x = __builtin_amdgcn_exp2f(acc[i][0] * SCALE_2LOG2E);
    v.y = __builtin_amdgcn_exp2f(acc[i][1] * SCALE_2LOG2E);
    v.z = __builtin_amdgcn_exp2f(acc[i][2] * SCALE_2LOG2E);
    v.w = __builtin_amdgcn_exp2f(acc[i][3] * SCALE_2LOG2E);
    *(float4*)&dst[((size_t)(b * 256 + ro + r0 + i)) * 256 + co + c0] = v;
  }
}

// ---------------------------------------------------------------------------
// Kernel 2: fused scores + softmax + PV.
//   score'[q,k] = sum_h (-2*wv[h]) / (1 + Eq[q][h]*Ek[h][k])
// Thread (qg = t>>8, tk = t&255) owns the FULL h-sum for row qg, col tk
// (no h-split, no partial combine). EkT is staged through LDS in 16-h slabs
// (16 KB) via global_load_lds, double-buffered: the score inner loop has ZERO
// global loads -> latency-immune regardless of L2/HBM behavior.
// 4-way sigmoid combine: sum_i w_i/d_i = (sum_i w_i prod_{j!=i} d_j)/prod d_j
// -> 1 rcp per 4 h (trans work /4). d_i = 1+e^2x >= 1, products <= ~1e24: safe.
// PV: UNCHANGED from round 7 (ablation control: if score-stall was dominant,
// attn drops to ~25us; if not, PV is the next staging target).
// ---------------------------------------------------------------------------
__global__ __launch_bounds__(1024) void attn_kernel(
    const float* __restrict__ Eq, const float* __restrict__ EkT,
    const float* __restrict__ wv, const float* __restrict__ values,
    float* __restrict__ out) {
  const int t  = threadIdx.x;
  const int qg = t >> 8;        // owned q-row (score/softmax); k-quarter (PV)
  const int tk = t & 255;       // owned k (score); dv-pair (PV)
  const int b  = blockIdx.x & 7;           // XCD-locality decode
  const int q0 = (blockIdx.x >> 3) * QB;

  __shared__ float ek_stage[2][16 * K_];  // 32 KB: two 16-h slabs
  __shared__ float eq_t[QB][H_];          // 4 KB  [qq][h] (contiguous per-row)
  __shared__ float wvm2[H_];              // 1 KB  (-2*wv)
  __shared__ float attn_t[K_][QB];        // 4 KB  [k][qq]
  __shared__ float2 pvscr[3 * QB * 256];  // 24 KB PV partials
  __shared__ float pmax[QB][4];
  __shared__ float psum[QB][4];

  const float* ek_base = EkT + (size_t)b * H_ * K_;
  const int lds_wbase = (t >> 6) << 8;    // wave's 256-float segment in slab

  // ---- issue stage of slab 0 first (latency hides under eq/wv staging) ----
  {
    const float* g = ek_base + 4 * t;
    __builtin_amdgcn_global_load_lds(
        (const __attribute__((address_space(1))) void*)g,
        (__attribute__((address_space(3))) void*)&ek_stage[0][lds_wbase],
        16, 0, 0);
  }
  if (t < H_) {
    const float* qs = Eq + ((size_t)(b * Q_ + q0)) * H_ + t;
    eq_t[0][t] = qs[0];
    eq_t[1][t] = qs[H_];
    eq_t[2][t] = qs[2 * H_];
    eq_t[3][t] = qs[3 * H_];
    wvm2[t] = -2.0f * wv[t];
  }
  __syncthreads();   // drains slab-0 DMA + publishes eq/wv

  // ---- score: 16 double-buffered slabs of 16 h; 4-way combined sigmoids ----
  float s2 = 0.0f;
  for (int c = 0; c < 16; c++) {
    if (c + 1 < 16) {
      const float* g = ek_base + (size_t)(c + 1) * (16 * K_) + 4 * t;
      __builtin_amdgcn_global_load_lds(
          (const __attribute__((address_space(1))) void*)g,
          (__attribute__((address_space(3))) void*)&ek_stage[(c + 1) & 1][lds_wbase],
          16, 0, 0);
    }
    const float* ek = &ek_stage[c & 1][0];
    const int hc = c * 16;
    #pragma unroll
    for (int g4 = 0; g4 < 4; g4++) {
      const int hl = g4 * 4;
      float ek0 = ek[(hl + 0) * K_ + tk];
      float ek1 = ek[(hl + 1) * K_ + tk];
      float ek2 = ek[(hl + 2) * K_ + tk];
      float ek3 = ek[(hl + 3) * K_ + tk];
      float4 eqv = *(const float4*)&eq_t[qg][hc + hl];   // broadcast b128
      float4 wvv = *(const float4*)&wvm2[hc + hl];       // broadcast b128
      float d0 = fmaf(eqv.x, ek0, 1.0f);
      float d1 = fmaf(eqv.y, ek1, 1.0f);
      float d2 = fmaf(eqv.z, ek2, 1.0f);
      float d3 = fmaf(eqv.w, ek3, 1.0f);
      float p01 = d0 * d1, p23 = d2 * d3;
      float n01 = fmaf(wvv.x, d1, wvv.y * d0);
      float n23 = fmaf(wvv.z, d3, wvv.w * d2);
      float num = fmaf(n01, p23, n23 * p01);
      float den = p01 * p23;
      s2 = fmaf(num, __builtin_amdgcn_rcpf(den), s2);
    }
    __syncthreads();  // drains next slab's DMA; fences ek reads before overwrite
  }

  // ---- softmax: thread holds complete sc for (row qg, col tk) ----
  const int wq = (t >> 6) & 3;  // wave index within q-group
  float sc = s2;
  float m = sc;
  #pragma unroll
  for (int mask = 32; mask >= 1; mask >>= 1) m = fmaxf(m, __shfl_xor(m, mask));
  if ((t & 63) == 0) pmax[qg][wq] = m;
  __syncthreads();
  float mx = fmaxf(fmaxf(pmax[qg][0], pmax[qg][1]), fmaxf(pmax[qg][2], pmax[qg][3]));
  float ev = __builtin_amdgcn_exp2f((sc - mx) * LOG2E_F);
  attn_t[tk][qg] = ev;
  float s = ev;
  #pragma unroll
  for (int mask = 32; mask >= 1; mask >>= 1) s += __shfl_xor(s, mask);
  if ((t & 63) == 0) psum[qg][wq] = s;
  __syncthreads();

  float rs[QB];
  #pragma unroll
  for (int qq = 0; qq < QB; qq++)
    rs[qq] = __builtin_amdgcn_rcpf(psum[qq][0] + psum[qq][1] + psum[qq][2] + psum[qq][3]);

  // ---- PV (unchanged, ablation control): quarter qg owns k in [64*qg,+64),
  //      thread owns dv pair tk; direct global loads ----
  float2 acc[QB];
  #pragma unroll
  for (int qq = 0; qq < QB; qq++) acc[qq] = make_float2(0.f, 0.f);
  const float2* vp = (const float2*)(values + (size_t)b * K_ * DV_) + tk;
  const int kbase = qg * 64;
  #pragma unroll 4
  for (int kk = 0; kk < 64; kk++) {
    const int k = kbase + kk;
    float2 v = vp[(size_t)k * (DV_ / 2)];
    float4 a = *(const float4*)&attn_t[k][0];
    acc[0].x = fmaf(a.x, v.x, acc[0].x); acc[0].y = fmaf(a.x, v.y, acc[0].y);
    acc[1].x = fmaf(a.y, v.x, acc[1].x); acc[1].y = fmaf(a.y, v.y, acc[1].y);
    acc[2].x = fmaf(a.z, v.x, acc[2].x); acc[2].y = fmaf(a.z, v.y, acc[2].y);
    acc[3].x = fmaf(a.w, v.x, acc[3].x); acc[3].y = fmaf(a.w, v.y, acc[3].y);
  }
  if (qg > 0) {
    #pragma unroll
    for (int qq = 0; qq < QB; qq++)
      pvscr[((qg - 1) * QB + qq) * 256 + tk] = acc[qq];
  }
  __syncthreads();
  if (qg == 0) {
    #pragma unroll
    for (int qq = 0; qq < QB; qq++) {
      float2 a1 = pvscr[(0 * QB + qq) * 256 + tk];
      float2 a2 = pvscr[(1 * QB + qq) * 256 + tk];
      float2 a3 = pvscr[(2 * QB + qq) * 256 + tk];
      float2 o;
      o.x = (acc[qq].x + a1.x + a2.x + a3.x) * rs[qq];
      o.y = (acc[qq].y + a1.y + a2.y + a3.y) * rs[qq];
      *(float2*)&out[((size_t)(b * Q_ + q0 + qq)) * DV_ + 2 * tk] = o;
    }
  }
}

extern "C" void kernel_launch(void* const* d_in, const int* in_sizes, int n_in,
                              void* d_out, int out_size, void* d_ws, size_t ws_size,
                              hipStream_t stream) {
  const float* queries = (const float*)d_in[0];  // [8,256,256]
  const float* keys    = (const float*)d_in[1];  // [8,256,256]
  const float* values  = (const float*)d_in[2];  // [8,256,512]
  const float* W_q     = (const float*)d_in[3];  // [256,256]
  const float* W_k     = (const float*)d_in[4];  // [256,256]
  const float* w_v     = (const float*)d_in[5];  // [256]
  float* out = (float*)d_out;

  float* Eq  = (float*)d_ws;                     // [8][256][256] = 2 MB
  float* EkT = Eq + (size_t)B_ * Q_ * H_;        // [8][256][256] = 2 MB

  dim3 pgrid(256), pblk(256);
  proj_kernel<<<pgrid, pblk, 0, stream>>>(queries, keys, W_q, W_k, Eq, EkT);

  dim3 agrid(Q_ / QB * B_), ablk(1024);
  attn_kernel<<<agrid, ablk, 0, stream>>>(Eq, EkT, w_v, values, out);
}

// Round 9
// 50.992 us; speedup vs baseline: 1.0789x; 1.0789x over previous
//
#include <hip/hip_runtime.h>
#include <hip/hip_bf16.h>

// Problem dims (fixed): B=8, Q=256, K=256, D=256, H=256, DV=512
#define B_  8
#define Q_  256
#define K_  256
#define D_  256
#define H_  256
#define DV_ 512
#define QB  4            // q-rows per attn block

#define SCALE_2LOG2E 2.8853900817779268f   // 2*log2(e): exp(2x) = 2^(x*this)
#define LOG2E_F      1.4426950408889634f

// ---------------------------------------------------------------------------
// Kernel 1: projections + exponentiation (exp factorization):
//   Eq [B][Q][H]  = 2^((queries @ W_q) * 2log2e)
//   EkT[B][H][K]  = 2^((keys    @ W_k)^T * 2log2e)   (transposed)
// Flat 1D grid, b = id&7 (XCD-locality with attn kernel's decode).
// ---------------------------------------------------------------------------
__global__ __launch_bounds__(256) void proj_kernel(
    const float* __restrict__ queries, const float* __restrict__ keys,
    const float* __restrict__ Wq, const float* __restrict__ Wk,
    float* __restrict__ Eq, float* __restrict__ EkT) {
  const int id = blockIdx.x;
  const int b  = id & 7;
  const bool kpath = (id >> 3) & 1;
  const int m0 = ((id >> 4) & 3) * 64;     // q-rows (qpath) or k-cols (kpath)
  const int h0 = ((id >> 6) & 3) * 64;
  const int tid = threadIdx.x;

  __shared__ float As[64][68];             // [d][row]
  __shared__ float Bs[64][68];             // [d][col]

  const int lr = tid >> 4;
  const int lc = (tid & 15) << 2;
  const int r0 = (tid & 15) << 2;
  const int c0 = (tid >> 4) << 2;

  float acc[4][4] = {};

  for (int kk = 0; kk < D_; kk += 64) {
    if (!kpath) {
      #pragma unroll
      for (int i = 0; i < 4; i++) {
        const int row = lr + i * 16;
        float4 va = *(const float4*)&queries[((size_t)(b * Q_ + m0 + row)) * D_ + kk + lc];
        As[lc + 0][row] = va.x; As[lc + 1][row] = va.y;
        As[lc + 2][row] = va.z; As[lc + 3][row] = va.w;
        float4 vb = *(const float4*)&Wq[((size_t)(kk + row)) * H_ + h0 + lc];
        *(float4*)&Bs[row][lc] = vb;
      }
    } else {
      #pragma unroll
      for (int i = 0; i < 4; i++) {
        const int row = lr + i * 16;
        float4 va = *(const float4*)&Wk[((size_t)(kk + row)) * H_ + h0 + lc];
        *(float4*)&As[row][lc] = va;
        float4 vb = *(const float4*)&keys[((size_t)(b * K_ + m0 + row)) * D_ + kk + lc];
        Bs[lc + 0][row] = vb.x; Bs[lc + 1][row] = vb.y;
        Bs[lc + 2][row] = vb.z; Bs[lc + 3][row] = vb.w;
      }
    }
    __syncthreads();

    #pragma unroll 8
    for (int d = 0; d < 64; d++) {
      float4 av = *(const float4*)&As[d][r0];
      float4 bv = *(const float4*)&Bs[d][c0];
      acc[0][0] = fmaf(av.x, bv.x, acc[0][0]); acc[0][1] = fmaf(av.x, bv.y, acc[0][1]);
      acc[0][2] = fmaf(av.x, bv.z, acc[0][2]); acc[0][3] = fmaf(av.x, bv.w, acc[0][3]);
      acc[1][0] = fmaf(av.y, bv.x, acc[1][0]); acc[1][1] = fmaf(av.y, bv.y, acc[1][1]);
      acc[1][2] = fmaf(av.y, bv.z, acc[1][2]); acc[1][3] = fmaf(av.y, bv.w, acc[1][3]);
      acc[2][0] = fmaf(av.z, bv.x, acc[2][0]); acc[2][1] = fmaf(av.z, bv.y, acc[2][1]);
      acc[2][2] = fmaf(av.z, bv.z, acc[2][2]); acc[2][3] = fmaf(av.z, bv.w, acc[2][3]);
      acc[3][0] = fmaf(av.w, bv.x, acc[3][0]); acc[3][1] = fmaf(av.w, bv.y, acc[3][1]);
      acc[3][2] = fmaf(av.w, bv.z, acc[3][2]); acc[3][3] = fmaf(av.w, bv.w, acc[3][3]);
    }
    __syncthreads();
  }

  float* dst = kpath ? EkT : Eq;
  const int ro = kpath ? h0 : m0, co = kpath ? m0 : h0;
  #pragma unroll
  for (int i = 0; i < 4; i++) {
    float4 v;
    v.x = __builtin_amdgcn_exp2f(acc[i][0] * SCALE_2LOG2E);
    v.y = __builtin_amdgcn_exp2f(acc[i][1] * SCALE_2LOG2E);
    v.z = __builtin_amdgcn_exp2f(acc[i][2] * SCALE_2LOG2E);
    v.w = __builtin_amdgcn_exp2f(acc[i][3] * SCALE_2LOG2E);
    *(float4*)&dst[((size_t)(b * 256 + ro + r0 + i)) * 256 + co + c0] = v;
  }
}

// ---------------------------------------------------------------------------
// Kernel 2: fused scores + softmax + PV — LDS-pipe-minimal repartition.
// Round-8 postmortem: the per-CU LDS pipe was the limiter (~97K cyc/CU).
// New layout (block = 16 waves, QB=4 q-rows):
//   SCORE: lane owns k = 4*lane..+3 (wave covers ALL 256 k), wave wid owns
//     h-chunk [16*wid, +16), all 4 q in registers (s2v[4] float4 over k).
//     ek read DIRECT from global as b128 (VMEM pipe, L2-resident, reg
//     double-buffer); eq/wv are 5 broadcast b128 LDS reads per 4-h step
//     (240 LDS cyc/wave total). Each (h,k) element touched once per block.
//   REDUCE: 4-step LDS tree (16->1 waves) over h-chunks; wave 0 then does
//     the entire softmax in-register (row = 4 in-lane + 64-lane shfl).
//   PV: wave = (k-range of 32) x (dv-half); lane owns 4 dv (b128 values
//     loads); 1 broadcast b128 attn read per k (12 LDS vs 32 VALU cyc).
//     Waves 0,1 combine the 7 partials and write out.
// ---------------------------------------------------------------------------
__global__ __launch_bounds__(1024) void attn_kernel(
    const float* __restrict__ Eq, const float* __restrict__ EkT,
    const float* __restrict__ wv, const float* __restrict__ values,
    float* __restrict__ out) {
  const int t    = threadIdx.x;
  const int wid  = t >> 6;
  const int lane = t & 63;
  const int b    = blockIdx.x & 7;          // XCD-locality decode
  const int q0   = (blockIdx.x >> 3) * QB;

  __shared__ float rbuf[14 * 64 * 16];     // 56 KB: h-tree (slots 0-7) / PV partials (0-13)
  __shared__ float eq_t[QB][H_];           // 4 KB
  __shared__ float wvm2[H_];               // 1 KB (-2*wv)
  __shared__ float attn_t[K_][QB];         // 4 KB
  __shared__ float psumS[QB];

  // ---- stage eq (4 rows) + wv ----
  if (t < H_) {
    const float* qs = Eq + ((size_t)(b * Q_ + q0)) * H_ + t;
    eq_t[0][t] = qs[0];
    eq_t[1][t] = qs[H_];
    eq_t[2][t] = qs[2 * H_];
    eq_t[3][t] = qs[3 * H_];
    wvm2[t] = -2.0f * wv[t];
  }
  __syncthreads();

  // ---- score: wave's 16-h chunk, 4-way h-combined sigmoids ----
  float4 s2v[QB];
  #pragma unroll
  for (int qq = 0; qq < QB; qq++) s2v[qq] = make_float4(0.f, 0.f, 0.f, 0.f);

  const int hbase = wid * 16;
  const float* ekb = EkT + (size_t)b * H_ * K_ + (size_t)hbase * K_ + 4 * lane;

  float4 ekc[4], ekn[4];
  #pragma unroll
  for (int j = 0; j < 4; j++) ekc[j] = *(const float4*)(ekb + (size_t)j * K_);

  #pragma unroll
  for (int st = 0; st < 4; st++) {
    if (st < 3) {
      #pragma unroll
      for (int j = 0; j < 4; j++)
        ekn[j] = *(const float4*)(ekb + (size_t)((st + 1) * 4 + j) * K_);
    }
    const int h = hbase + st * 4;
    float4 wvv = *(const float4*)&wvm2[h];
    #pragma unroll
    for (int qq = 0; qq < QB; qq++) {
      float4 eqv = *(const float4*)&eq_t[qq][h];
      float4 s2q = s2v[qq];
      // one k-component per macro expansion (4 h combined per rcp)
      #define SCORE_K(C)                                                      \
      {                                                                       \
        float d0 = fmaf(eqv.x, ekc[0].C, 1.0f);                               \
        float d1 = fmaf(eqv.y, ekc[1].C, 1.0f);                               \
        float d2 = fmaf(eqv.z, ekc[2].C, 1.0f);                               \
        float d3 = fmaf(eqv.w, ekc[3].C, 1.0f);                               \
        float p01 = d0 * d1, p23 = d2 * d3;                                   \
        float n01 = fmaf(wvv.x, d1, wvv.y * d0);                              \
        float n23 = fmaf(wvv.z, d3, wvv.w * d2);                              \
        float num = fmaf(n01, p23, n23 * p01);                                \
        s2q.C = fmaf(num, __builtin_amdgcn_rcpf(p01 * p23), s2q.C);           \
      }
      SCORE_K(x) SCORE_K(y) SCORE_K(z) SCORE_K(w)
      #undef SCORE_K
      s2v[qq] = s2q;
    }
    #pragma unroll
    for (int j = 0; j < 4; j++) ekc[j] = ekn[j];
  }

  // ---- h-chunk tree reduce: 16 -> 1 waves (slots 0..7 of rbuf) ----
  #pragma unroll
  for (int s = 8; s >= 1; s >>= 1) {
    if (wid >= s && wid < 2 * s) {
      float* w = &rbuf[(wid - s) * 1024 + lane * 16];
      #pragma unroll
      for (int qq = 0; qq < QB; qq++) *(float4*)&w[qq * 4] = s2v[qq];
    }
    __syncthreads();
    if (wid < s) {
      const float* r = &rbuf[wid * 1024 + lane * 16];
      #pragma unroll
      for (int qq = 0; qq < QB; qq++) {
        float4 p = *(const float4*)&r[qq * 4];
        s2v[qq].x += p.x; s2v[qq].y += p.y; s2v[qq].z += p.z; s2v[qq].w += p.w;
      }
    }
    __syncthreads();
  }

  // ---- softmax entirely on wave 0 (lane holds k = 4*lane..+3) ----
  if (wid == 0) {
    float4 evq[QB];
    #pragma unroll
    for (int qq = 0; qq < QB; qq++) {
      float4 v = s2v[qq];
      float m = fmaxf(fmaxf(v.x, v.y), fmaxf(v.z, v.w));
      #pragma unroll
      for (int mask = 32; mask >= 1; mask >>= 1) m = fmaxf(m, __shfl_xor(m, mask));
      float4 e;
      e.x = __builtin_amdgcn_exp2f((v.x - m) * LOG2E_F);
      e.y = __builtin_amdgcn_exp2f((v.y - m) * LOG2E_F);
      e.z = __builtin_amdgcn_exp2f((v.z - m) * LOG2E_F);
      e.w = __builtin_amdgcn_exp2f((v.w - m) * LOG2E_F);
      float sl = (e.x + e.y) + (e.z + e.w);
      #pragma unroll
      for (int mask = 32; mask >= 1; mask >>= 1) sl += __shfl_xor(sl, mask);
      if (lane == 0) psumS[qq] = sl;
      evq[qq] = e;
    }
    // transpose to attn_t[k][qq] (b128 per k-row)
    float4 a0 = make_float4(evq[0].x, evq[1].x, evq[2].x, evq[3].x);
    float4 a1 = make_float4(evq[0].y, evq[1].y, evq[2].y, evq[3].y);
    float4 a2 = make_float4(evq[0].z, evq[1].z, evq[2].z, evq[3].z);
    float4 a3 = make_float4(evq[0].w, evq[1].w, evq[2].w, evq[3].w);
    *(float4*)&attn_t[4 * lane + 0][0] = a0;
    *(float4*)&attn_t[4 * lane + 1][0] = a1;
    *(float4*)&attn_t[4 * lane + 2][0] = a2;
    *(float4*)&attn_t[4 * lane + 3][0] = a3;
  }
  __syncthreads();

  // ---- PV: wave = (kr = wid>>1 owns 32 k) x (dvh = wid&1); lane owns 4 dv ----
  const int kr  = wid >> 1;
  const int dvh = wid & 1;
  const float* vbase = values + (size_t)b * K_ * DV_ + dvh * 256 + 4 * lane;
  float4 pacc[QB];
  #pragma unroll
  for (int qq = 0; qq < QB; qq++) pacc[qq] = make_float4(0.f, 0.f, 0.f, 0.f);
  #pragma unroll 4
  for (int kk = 0; kk < 32; kk++) {
    const int k = kr * 32 + kk;
    float4 a = *(const float4*)&attn_t[k][0];
    float4 v = *(const float4*)(vbase + (size_t)k * DV_);
    pacc[0].x = fmaf(a.x, v.x, pacc[0].x); pacc[0].y = fmaf(a.x, v.y, pacc[0].y);
    pacc[0].z = fmaf(a.x, v.z, pacc[0].z); pacc[0].w = fmaf(a.x, v.w, pacc[0].w);
    pacc[1].x = fmaf(a.y, v.x, pacc[1].x); pacc[1].y = fmaf(a.y, v.y, pacc[1].y);
    pacc[1].z = fmaf(a.y, v.z, pacc[1].z); pacc[1].w = fmaf(a.y, v.w, pacc[1].w);
    pacc[2].x = fmaf(a.z, v.x, pacc[2].x); pacc[2].y = fmaf(a.z, v.y, pacc[2].y);
    pacc[2].z = fmaf(a.z, v.z, pacc[2].z); pacc[2].w = fmaf(a.z, v.w, pacc[2].w);
    pacc[3].x = fmaf(a.w, v.x, pacc[3].x); pacc[3].y = fmaf(a.w, v.y, pacc[3].y);
    pacc[3].z = fmaf(a.w, v.z, pacc[3].z); pacc[3].w = fmaf(a.w, v.w, pacc[3].w);
  }
  if (wid >= 2) {
    float* w = &rbuf[(wid - 2) * 1024 + lane * 16];
    #pragma unroll
    for (int qq = 0; qq < QB; qq++) *(float4*)&w[qq * 4] = pacc[qq];
  }
  __syncthreads();
  if (wid < 2) {
    #pragma unroll
    for (int p = 0; p < 7; p++) {
      const float* r = &rbuf[(wid + 2 * p) * 1024 + lane * 16];
      #pragma unroll
      for (int qq = 0; qq < QB; qq++) {
        float4 pp = *(const float4*)&r[qq * 4];
        pacc[qq].x += pp.x; pacc[qq].y += pp.y; pacc[qq].z += pp.z; pacc[qq].w += pp.w;
      }
    }
    #pragma unroll
    for (int qq = 0; qq < QB; qq++) {
      float rs = __builtin_amdgcn_rcpf(psumS[qq]);
      float4 o = make_float4(pacc[qq].x * rs, pacc[qq].y * rs,
                             pacc[qq].z * rs, pacc[qq].w * rs);
      *(float4*)&out[((size_t)(b * Q_ + q0 + qq)) * DV_ + dvh * 256 + 4 * lane] = o;
    }
  }
}

extern "C" void kernel_launch(void* const* d_in, const int* in_sizes, int n_in,
                              void* d_out, int out_size, void* d_ws, size_t ws_size,
                              hipStream_t stream) {
  const float* queries = (const float*)d_in[0];  // [8,256,256]
  const float* keys    = (const float*)d_in[1];  // [8,256,256]
  const float* values  = (const float*)d_in[2];  // [8,256,512]
  const float* W_q     = (const float*)d_in[3];  // [256,256]
  const float* W_k     = (const float*)d_in[4];  // [256,256]
  const float* w_v     = (const float*)d_in[5];  // [256]
  float* out = (float*)d_out;

  float* Eq  = (float*)d_ws;                     // [8][256][256] = 2 MB
  float* EkT = Eq + (size_t)B_ * Q_ * H_;        // [8][256][256] = 2 MB

  dim3 pgrid(256), pblk(256);
  proj_kernel<<<pgrid, pblk, 0, stream>>>(queries, keys, W_q, W_k, Eq, EkT);

  dim3 agrid(Q_ / QB * B_), ablk(1024);
  attn_kernel<<<agrid, ablk, 0, stream>>>(Eq, EkT, w_v, values, out);
}